// Round 9
// baseline (308.712 us; speedup 1.0000x reference)
//
#include <hip/hip_runtime.h>
#include <hip/hip_bf16.h>
#include <math.h>

// Problem constants
#define Bc   2
#define Tc   2048
#define Cc   1024
#define Hc   16
#define HSc  64
#define WSZ  128
#define BLKc 64
#define NBc  32
#define NSELc 8
#define Mrows (Bc*Tc)   // 4096
#define QCH  32         // qbar chunks over T
#define LST  88         // K/V LDS ushort row stride (176 B; 8 rows tile 32 banks)
#define LSTP 68         // Ph LDS ushort row stride (34 dw = +2 banks/row)
#define MAXT 12         // max tiles per fattn block (3 slide + 8 sel + 1 cmp)
#define SOFT_C 4.0f     // constant softmax shift (scores |s| << 4; exact ratio)

typedef __attribute__((ext_vector_type(8))) _Float16 half8;  // 8 fp16 in 4 VGPRs
typedef __attribute__((ext_vector_type(4))) float f32x4v;
typedef __attribute__((ext_vector_type(8))) unsigned short ushort8v;

__device__ __forceinline__ float wave_sum(float v) {
    #pragma unroll
    for (int o = 32; o; o >>= 1) v += __shfl_xor(v, o);
    return v;
}

__device__ __forceinline__ unsigned short f2h(float f) {
    _Float16 h = (_Float16)f;
    unsigned short u;
    __builtin_memcpy(&u, &h, 2);
    return u;
}
__device__ __forceinline__ float h2f(unsigned short u) {
    _Float16 h;
    __builtin_memcpy(&h, &u, 2);
    return (float)h;
}

// async global->LDS, 16B per lane; LDS dest = base + lane*16 (wave-uniform base)
__device__ __forceinline__ void gload16(const void* g, void* l) {
    __builtin_amdgcn_global_load_lds(
        (const __attribute__((address_space(1))) void*)g,
        (__attribute__((address_space(3))) void*)l, 16, 0, 0);
}

// ---------------------------------------------------------------------------
// fp32 -> fp16 (bits) elementwise. n = grid*256*4 elements exactly.
// ---------------------------------------------------------------------------
__global__ __launch_bounds__(256)
void cvt_f16_kernel(const float* __restrict__ src, unsigned short* __restrict__ dst)
{
    int i = (blockIdx.x * 256 + threadIdx.x) * 4;
    float4 v = *(const float4*)&src[i];
    ushort4 o;
    o.x = f2h(v.x); o.y = f2h(v.y); o.z = f2h(v.z); o.w = f2h(v.w);
    *(ushort4*)&dst[i] = o;
}

// ---------------------------------------------------------------------------
// 4x W (1024x1024 fp32) -> WT (N x K fp16). z<3 -> D012 (concat QKV), z==3 -> D3.
// ---------------------------------------------------------------------------
__global__ __launch_bounds__(256)
void cvt_wT4_kernel(const float* __restrict__ W0, const float* __restrict__ W1,
                    const float* __restrict__ W2, const float* __restrict__ W3,
                    unsigned short* __restrict__ D012, unsigned short* __restrict__ D3)
{
    __shared__ float tile[64][65];
    const int z = blockIdx.z;
    const float* W = (z == 0) ? W0 : (z == 1) ? W1 : (z == 2) ? W2 : W3;
    unsigned short* WT = (z < 3) ? (D012 + (size_t)z * 1024 * 1024) : D3;
    const int n0 = blockIdx.x * 64, k0 = blockIdx.y * 64;
    const int tid = threadIdx.x;
    #pragma unroll
    for (int it = 0; it < 16; ++it) {
        int lin = tid + it * 256;
        int r = lin >> 6, c = lin & 63;          // r = k, c = n
        tile[r][c] = W[(size_t)(k0 + r) * 1024 + n0 + c];
    }
    __syncthreads();
    #pragma unroll
    for (int it = 0; it < 16; ++it) {
        int lin = tid + it * 256;
        int n = lin >> 6, k = lin & 63;
        WT[(size_t)(n0 + n) * 1024 + k0 + k] = f2h(tile[k][n]);
    }
}

// ---------------------------------------------------------------------------
// Fused QKV fp16 MFMA GEMM, BK=64 (32 MFMAs/barrier). BT = concat WqkvT.
// Q -> fp32 (b,h,t,d); K -> fp16 (b,h,t,d); V -> fp16 row-major.
// ---------------------------------------------------------------------------
__global__ __launch_bounds__(256)
void mfma_gemm_qkv(const unsigned short* __restrict__ A,
                   const unsigned short* __restrict__ BT,
                   const float* __restrict__ bq, const float* __restrict__ bk,
                   const float* __restrict__ bv,
                   float* __restrict__ Qw, unsigned short* __restrict__ Kf,
                   unsigned short* __restrict__ Vf)
{
    constexpr int K = 1024;
    __shared__ unsigned short As[8 * 128 * 8];   // 16 KB
    __shared__ unsigned short Bs[8 * 128 * 8];   // 16 KB
    const int tid  = threadIdx.x;
    const int lane = tid & 63;
    const int wid  = tid >> 6;
    const int m0 = blockIdx.y * 128, n0 = blockIdx.x * 128;
    const int wm = (wid >> 1) * 64, wn = (wid & 1) * 64;

    f32x4v acc[4][4];
    #pragma unroll
    for (int i = 0; i < 4; ++i)
        #pragma unroll
        for (int j = 0; j < 4; ++j)
            acc[i][j] = (f32x4v){0.f, 0.f, 0.f, 0.f};

    const int kq_r = lane >> 4;
    const int r16  = lane & 15;

    for (int k0 = 0; k0 < K; k0 += 64) {
        __syncthreads();
        #pragma unroll
        for (int it = 0; it < 4; ++it) {
            int cell = wid * 64 + it * 256 + lane;    // 0..1023
            int kq = cell >> 7, row = cell & 127;
            gload16(A  + (size_t)(m0 + row) * K + k0 + kq * 8,
                    As + (size_t)(wid * 64 + it * 256) * 8);
            gload16(BT + (size_t)(n0 + row) * K + k0 + kq * 8,
                    Bs + (size_t)(wid * 64 + it * 256) * 8);
        }
        __syncthreads();

        #pragma unroll
        for (int p = 0; p < 2; ++p) {
            half8 af[4], bf[4];
            #pragma unroll
            for (int i = 0; i < 4; ++i)
                af[i] = *(const half8*)&As[(size_t)((p * 4 + kq_r) * 128 + wm + i * 16 + r16) * 8];
            #pragma unroll
            for (int j = 0; j < 4; ++j)
                bf[j] = *(const half8*)&Bs[(size_t)((p * 4 + kq_r) * 128 + wn + j * 16 + r16) * 8];
            #pragma unroll
            for (int i = 0; i < 4; ++i)
                #pragma unroll
                for (int j = 0; j < 4; ++j)
                    acc[i][j] = __builtin_amdgcn_mfma_f32_16x16x32_f16(af[i], bf[j], acc[i][j], 0, 0, 0);
        }
    }

    const int which = n0 >> 10;   // 0=Q 1=K 2=V (block-uniform)
    const float* bias = (which == 0) ? bq : ((which == 1) ? bk : bv);

    #pragma unroll
    for (int i = 0; i < 4; ++i) {
        int mbase = m0 + wm + i * 16 + (lane >> 4) * 4;
        #pragma unroll
        for (int j = 0; j < 4; ++j) {
            int n = n0 + wn + j * 16 + (lane & 15);
            int nn = n & 1023;
            float bvv = bias[nn];
            int h = nn >> 6, d = nn & 63;
            #pragma unroll
            for (int r = 0; r < 4; ++r) {
                int m = mbase + r;
                int b = m >> 11, t = m & 2047;
                float v = acc[i][j][r] + bvv;
                size_t idx = (((size_t)(b * Hc + h) * Tc) + t) * HSc + d;
                if (which == 0)      Qw[idx] = v;
                else if (which == 1) Kf[idx] = f2h(v);
                else                 Vf[idx] = f2h(v);
            }
        }
    }
}

// ---------------------------------------------------------------------------
// fp16 MFMA GEMM (row-major fp32 out), BK=64: final projection.
// ---------------------------------------------------------------------------
__global__ __launch_bounds__(256)
void mfma_gemm_kernel(const unsigned short* __restrict__ A,
                      const unsigned short* __restrict__ BT,
                      const float* __restrict__ bias,
                      float* __restrict__ Y)
{
    constexpr int K = 1024;
    __shared__ unsigned short As[8 * 128 * 8];
    __shared__ unsigned short Bs[8 * 128 * 8];
    const int tid  = threadIdx.x;
    const int lane = tid & 63;
    const int wid  = tid >> 6;
    const int m0 = blockIdx.y * 128, n0 = blockIdx.x * 128;
    const int wm = (wid >> 1) * 64, wn = (wid & 1) * 64;

    f32x4v acc[4][4];
    #pragma unroll
    for (int i = 0; i < 4; ++i)
        #pragma unroll
        for (int j = 0; j < 4; ++j)
            acc[i][j] = (f32x4v){0.f, 0.f, 0.f, 0.f};

    const int kq_r = lane >> 4;
    const int r16  = lane & 15;

    for (int k0 = 0; k0 < K; k0 += 64) {
        __syncthreads();
        #pragma unroll
        for (int it = 0; it < 4; ++it) {
            int cell = wid * 64 + it * 256 + lane;
            int kq = cell >> 7, row = cell & 127;
            gload16(A  + (size_t)(m0 + row) * K + k0 + kq * 8,
                    As + (size_t)(wid * 64 + it * 256) * 8);
            gload16(BT + (size_t)(n0 + row) * K + k0 + kq * 8,
                    Bs + (size_t)(wid * 64 + it * 256) * 8);
        }
        __syncthreads();

        #pragma unroll
        for (int p = 0; p < 2; ++p) {
            half8 af[4], bf[4];
            #pragma unroll
            for (int i = 0; i < 4; ++i)
                af[i] = *(const half8*)&As[(size_t)((p * 4 + kq_r) * 128 + wm + i * 16 + r16) * 8];
            #pragma unroll
            for (int j = 0; j < 4; ++j)
                bf[j] = *(const half8*)&Bs[(size_t)((p * 4 + kq_r) * 128 + wn + j * 16 + r16) * 8];
            #pragma unroll
            for (int i = 0; i < 4; ++i)
                #pragma unroll
                for (int j = 0; j < 4; ++j)
                    acc[i][j] = __builtin_amdgcn_mfma_f32_16x16x32_f16(af[i], bf[j], acc[i][j], 0, 0, 0);
        }
    }

    #pragma unroll
    for (int i = 0; i < 4; ++i) {
        int mbase = m0 + wm + i * 16 + (lane >> 4) * 4;
        #pragma unroll
        for (int j = 0; j < 4; ++j) {
            int n = n0 + wn + j * 16 + (lane & 15);
            float bv = bias[n];
            #pragma unroll
            for (int r = 0; r < 4; ++r)
                Y[(size_t)(mbase + r) * 1024 + n] = acc[i][j][r] + bv;
        }
    }
}

// ---------------------------------------------------------------------------
// V (bh,t,d) fp16 -> Vt (bh,d,t) fp16. grid (Tc/64, B*H), 256 thr.
// ---------------------------------------------------------------------------
__global__ __launch_bounds__(256)
void vtrans_kernel(const unsigned short* __restrict__ Vf, unsigned short* __restrict__ Vt)
{
    __shared__ unsigned short tile[64][65];
    const int t0 = blockIdx.x * 64, bh = blockIdx.y;
    const int tid = threadIdx.x;
    const int c4 = (tid & 15) * 4, r = tid >> 4;   // 16 rows/iter
    const unsigned short* src = Vf + ((size_t)bh * Tc + t0) * HSc;
    #pragma unroll
    for (int it = 0; it < 4; ++it) {
        int tt = r + it * 16;
        *(ushort4*)&tile[tt][c4] = *(const ushort4*)&src[(size_t)tt * HSc + c4];
    }
    __syncthreads();
    unsigned short* dst = Vt + (size_t)bh * HSc * Tc + t0;
    #pragma unroll
    for (int it = 0; it < 4; ++it) {
        int d = r + it * 16;
        ushort4 o;
        o.x = tile[c4 + 0][d]; o.y = tile[c4 + 1][d];
        o.z = tile[c4 + 2][d]; o.w = tile[c4 + 3][d];
        *(ushort4*)&dst[(size_t)d * Tc + c4] = o;
    }
}

// ---------------------------------------------------------------------------
// Gates: one wave per row (4 rows/block), float4 loads.
// ---------------------------------------------------------------------------
__global__ __launch_bounds__(256)
void gates_kernel(const float* __restrict__ x, const float* __restrict__ Wg,
                  const float* __restrict__ bg, float* __restrict__ gates)
{
    const int row  = blockIdx.x * 4 + (threadIdx.x >> 6);
    const int lane = threadIdx.x & 63;
    const float* xr = x + (size_t)row * Cc;
    float p0 = 0, p1 = 0, p2 = 0;
    #pragma unroll
    for (int it = 0; it < 4; ++it) {
        int k4 = lane * 4 + it * 256;
        float4 xv = *(const float4*)&xr[k4];
        float4 w0 = *(const float4*)&Wg[k4 * 3];
        float4 w1 = *(const float4*)&Wg[k4 * 3 + 4];
        float4 w2 = *(const float4*)&Wg[k4 * 3 + 8];
        p0 += xv.x * w0.x + xv.y * w0.w + xv.z * w1.z + xv.w * w2.y;
        p1 += xv.x * w0.y + xv.y * w1.x + xv.z * w1.w + xv.w * w2.z;
        p2 += xv.x * w0.z + xv.y * w1.y + xv.z * w2.x + xv.w * w2.w;
    }
    p0 = wave_sum(p0); p1 = wave_sum(p1); p2 = wave_sum(p2);
    if (lane == 0) {
        p0 += bg[0]; p1 += bg[1]; p2 += bg[2];
        float m = fmaxf(p0, fmaxf(p1, p2));
        float e0 = expf(p0 - m), e1 = expf(p1 - m), e2 = expf(p2 - m);
        float s = e0 + e1 + e2;
        gates[row * 3 + 0] = e0 / s;
        gates[row * 3 + 1] = e1 / s;
        gates[row * 3 + 2] = e2 / s;
    }
}

// ---------------------------------------------------------------------------
// Per-block K/V means -> fp32 krep (topk) + zero-padded fp16 staging buffers.
// ---------------------------------------------------------------------------
__global__ __launch_bounds__(64)
void blockstats_kernel(const unsigned short* __restrict__ Kf,
                       const unsigned short* __restrict__ Vt,
                       float* __restrict__ krep,
                       unsigned short* __restrict__ krep16,
                       unsigned short* __restrict__ vcmpT16)
{
    int nb = blockIdx.x, bh = blockIdx.y, d = threadIdx.x;
    if (nb < NBc) {
        const unsigned short* kp = Kf + ((size_t)bh * Tc + nb * BLKc) * HSc + d;
        const unsigned short* vp = Vt + ((size_t)bh * HSc + d) * Tc + nb * BLKc;
        float sk = 0, sv = 0;
        #pragma unroll 8
        for (int j = 0; j < BLKc; j++) {
            sk += h2f(kp[(size_t)j * HSc]);
            sv += h2f(vp[j]);
        }
        float km = sk * (1.0f / BLKc), vm = sv * (1.0f / BLKc);
        krep[((size_t)bh * NBc + nb) * HSc + d] = km;
        krep16[(size_t)bh * 4096 + nb * 64 + d] = f2h(km);
        vcmpT16[(size_t)bh * 4096 + d * 64 + nb] = f2h(vm);
    } else {
        krep16[(size_t)bh * 4096 + nb * 64 + d] = 0;
        vcmpT16[(size_t)bh * 4096 + d * 64 + nb] = 0;
    }
}

// ---------------------------------------------------------------------------
// qbar partials: chunk c covers rows [c*64, c*64+64) of one (b,h).
// ---------------------------------------------------------------------------
__global__ __launch_bounds__(64)
void qbar_part_kernel(const float* __restrict__ Q, float* __restrict__ qpart)
{
    int ch = blockIdx.x, bh = blockIdx.y, d = threadIdx.x;
    int t0 = ch * (Tc / QCH);
    float acc = 0.0f;
    for (int it = 0; it < Tc / QCH; it++) {
        float v = Q[((size_t)bh * Tc + t0 + it) * HSc + d];
        float sq = wave_sum(v * v);
        float nrm = fmaxf(sqrtf(sq), 1e-8f);
        acc += v / nrm;
    }
    qpart[((size_t)bh * QCH + ch) * HSc + d] = acc;
}

// ---------------------------------------------------------------------------
// Selection scores + top-8 (descending, ties -> lower index)
// ---------------------------------------------------------------------------
__global__ __launch_bounds__(64)
void topk_kernel(const float* __restrict__ qpart, const float* __restrict__ krep,
                 int* __restrict__ topidx)
{
    int bh = blockIdx.x, lane = threadIdx.x;
    __shared__ float sc[NBc];
    __shared__ float qbs[HSc];
    float qa = 0.0f;
    #pragma unroll
    for (int c = 0; c < QCH; c++)
        qa += qpart[((size_t)bh * QCH + c) * HSc + lane];
    qbs[lane] = qa * (1.0f / Tc);
    __syncthreads();
    if (lane < NBc) {
        float dot = 0, nk = 0;
        for (int d = 0; d < HSc; d++) {
            float kv = krep[((size_t)bh * NBc + lane) * HSc + d];
            nk += kv * kv;
            dot += qbs[d] * kv;
        }
        sc[lane] = dot / fmaxf(sqrtf(nk), 1e-8f);
    }
    __syncthreads();
    if (lane == 0) {
        for (int s = 0; s < NSELc; s++) {
            int best = 0; float bv = sc[0];
            for (int n = 1; n < NBc; n++)
                if (sc[n] > bv) { bv = sc[n]; best = n; }
            topidx[bh * NSELc + s] = best;
            sc[best] = -INFINITY;
        }
    }
}

// ===========================================================================
// MFMA flash attention, constant-shift softmax, ones-MFMA row sums,
// pipelined flat tile loop, dbuf staging, fp16 output (feeds final GEMM).
// ===========================================================================
__device__ __forceinline__ void attn_tile3(
    int p0, int wlim, int klim, int qg0,
    const unsigned short* __restrict__ Kh, const unsigned short* __restrict__ Vt,
    unsigned short* __restrict__ Ph,
    half8 aq0, half8 aq1, half8 ones, int wq, int l16, int quad,
    f32x4v o[4], f32x4v& o5)
{
    // ---- QK^T: 8 MFMAs ----
    f32x4v s[4];
    #pragma unroll
    for (int t = 0; t < 4; ++t) {
        f32x4v sa = (f32x4v){0.f, 0.f, 0.f, 0.f};
        half8 b0 = *(const half8*)&Kh[(t * 16 + l16) * LST + quad * 8];
        half8 b1 = *(const half8*)&Kh[(t * 16 + l16) * LST + 32 + quad * 8];
        sa = __builtin_amdgcn_mfma_f32_16x16x32_f16(aq0, b0, sa, 0, 0, 0);
        sa = __builtin_amdgcn_mfma_f32_16x16x32_f16(aq1, b1, sa, 0, 0, 0);
        s[t] = sa;
    }

    // ---- mask + P = exp(s - C) -> Ph (wave-private rows) ----
    #pragma unroll
    for (int t = 0; t < 4; ++t) {
        int kk = t * 16 + l16;
        bool kok = kk < klim;
        int jt = p0 + kk;
        #pragma unroll
        for (int r = 0; r < 4; ++r) {
            int q = qg0 + r;
            bool valid = kok && (jt <= q) && (q - jt <= wlim);
            float p = valid ? __expf(s[t][r] - SOFT_C) : 0.0f;
            Ph[(wq + quad * 4 + r) * LSTP + t * 16 + l16] = f2h(p);
        }
    }

    // NO barrier: Ph write/read is same-wave (lgkmcnt-ordered)

    // ---- PV: 8 MFMAs + 2 ones-MFMAs (row sums into o5) ----
    half8 ap0 = *(const half8*)&Ph[(wq + l16) * LSTP + quad * 8];
    half8 ap1 = *(const half8*)&Ph[(wq + l16) * LSTP + 32 + quad * 8];
    o5 = __builtin_amdgcn_mfma_f32_16x16x32_f16(ap0, ones, o5, 0, 0, 0);
    o5 = __builtin_amdgcn_mfma_f32_16x16x32_f16(ap1, ones, o5, 0, 0, 0);
    #pragma unroll
    for (int dt = 0; dt < 4; ++dt) {
        half8 v0 = *(const half8*)&Vt[(dt * 16 + l16) * LST + quad * 8];
        half8 v1 = *(const half8*)&Vt[(dt * 16 + l16) * LST + 32 + quad * 8];
        o[dt] = __builtin_amdgcn_mfma_f32_16x16x32_f16(ap0, v0, o[dt], 0, 0, 0);
        o[dt] = __builtin_amdgcn_mfma_f32_16x16x32_f16(ap1, v1, o[dt], 0, 0, 0);
    }
}

__global__ __launch_bounds__(256)
void fattn_kernel(const float* __restrict__ Q, const unsigned short* __restrict__ Kf,
                  const unsigned short* __restrict__ Vtg,
                  const unsigned short* __restrict__ krep16,
                  const unsigned short* __restrict__ vcmpT16,
                  const int* __restrict__ topidx,
                  const float* __restrict__ gates, unsigned short* __restrict__ merged)
{
    __shared__ unsigned short KH[2][64 * LST];
    __shared__ unsigned short VT[2][64 * LST];
    __shared__ unsigned short Ph[64 * LSTP];
    __shared__ float gsl[3 * 64];
    __shared__ int tKb[MAXT], tP0[MAXT], tWl[MAXT], tKl[MAXT], tBid[MAXT];

    const int qt = blockIdx.x;      // 0..31
    const int bh = blockIdx.y;      // 0..31
    const int b  = bh >> 4, h = bh & 15;
    const int tid  = threadIdx.x;
    const int wid  = tid >> 6, lane = tid & 63;
    const int l16  = lane & 15, quad = lane >> 4;
    const int q0 = qt * 64;
    const int wq = wid * 16;
    const int qg0 = q0 + wq + quad * 4;   // global q row of reg 0

    const int nslide = (qt < 2 ? qt : 2) + 1;
    const int nsel   = (qt + 1 < NSELc) ? (qt + 1) : NSELc;
    const int nt     = nslide + nsel + 1;

    // ---- Q fragments directly from global (one-time), ones fragment ----
    half8 aq0, aq1, ones;
    {
        const float* qrow = Q + ((size_t)bh * Tc + q0 + wq + l16) * HSc;
        float4 qa = ((const float4*)qrow)[quad * 2];
        float4 qb = ((const float4*)qrow)[quad * 2 + 1];
        float4 qc = ((const float4*)qrow)[quad * 2 + 8];
        float4 qd = ((const float4*)qrow)[quad * 2 + 9];
        aq0[0] = (_Float16)(qa.x * 0.125f); aq0[1] = (_Float16)(qa.y * 0.125f);
        aq0[2] = (_Float16)(qa.z * 0.125f); aq0[3] = (_Float16)(qa.w * 0.125f);
        aq0[4] = (_Float16)(qb.x * 0.125f); aq0[5] = (_Float16)(qb.y * 0.125f);
        aq0[6] = (_Float16)(qb.z * 0.125f); aq0[7] = (_Float16)(qb.w * 0.125f);
        aq1[0] = (_Float16)(qc.x * 0.125f); aq1[1] = (_Float16)(qc.y * 0.125f);
        aq1[2] = (_Float16)(qc.z * 0.125f); aq1[3] = (_Float16)(qc.w * 0.125f);
        aq1[4] = (_Float16)(qd.x * 0.125f); aq1[5] = (_Float16)(qd.y * 0.125f);
        aq1[6] = (_Float16)(qd.z * 0.125f); aq1[7] = (_Float16)(qd.w * 0.125f);
        #pragma unroll
        for (int j = 0; j < 8; ++j) ones[j] = (_Float16)1.0f;
    }

    if (tid < 64) {
        size_t gb = ((size_t)b * Tc + q0 + tid) * 3;
        gsl[0 * 64 + tid] = gates[gb + 0];
        gsl[1 * 64 + tid] = gates[gb + 1];
        gsl[2 * 64 + tid] = gates[gb + 2];
    }
    // ---- build tile descriptor list ----
    if (tid < nt) {
        int i = tid, kb, p0, wl, kl, bid;
        if (i < nslide)            { int tb = q0 - (nslide - 1 - i) * 64;
                                     kb = tb; p0 = tb; wl = WSZ; kl = 64; bid = 0; }
        else if (i < nslide + nsel){ int s = i - nslide;
                                     kb = topidx[bh * NSELc + s] * BLKc;
                                     p0 = s * BLKc; wl = 1 << 30; kl = 64; bid = 1; }
        else                       { kb = 0; p0 = 0; wl = 1 << 30; kl = NBc; bid = 2; }
        tKb[i] = kb; tP0[i] = p0; tWl[i] = wl; tKl[i] = kl; tBid[i] = bid;
    }

    f32x4v o[4], macc[4];
    f32x4v o5 = (f32x4v){0.f, 0.f, 0.f, 0.f};
    #pragma unroll
    for (int dt = 0; dt < 4; ++dt) {
        o[dt]    = (f32x4v){0.f, 0.f, 0.f, 0.f};
        macc[dt] = (f32x4v){0.f, 0.f, 0.f, 0.f};
    }

    const int seg = tid & 7, r0 = tid >> 3;   // 8 segs x 32 rows
    const unsigned short* kbh = Kf  + (size_t)bh * Tc * HSc;
    const unsigned short* vbh = Vtg + (size_t)bh * HSc * Tc;

    // ---- stage tile 0 (always sliding) into buffer 0 ----
    {
        int tb0 = q0 - (nslide - 1) * 64;
        const unsigned short* kp = kbh + (size_t)tb0 * HSc;
        const unsigned short* vp = vbh + tb0;
        ushort8v k0 = *(const ushort8v*)(kp + (size_t)r0 * HSc + seg * 8);
        ushort8v k1 = *(const ushort8v*)(kp + (size_t)(r0 + 32) * HSc + seg * 8);
        ushort8v v0 = *(const ushort8v*)(vp + (size_t)r0 * Tc + seg * 8);
        ushort8v v1 = *(const ushort8v*)(vp + (size_t)(r0 + 32) * Tc + seg * 8);
        *(ushort8v*)&KH[0][r0 * LST + seg * 8] = k0;
        *(ushort8v*)&KH[0][(r0 + 32) * LST + seg * 8] = k1;
        *(ushort8v*)&VT[0][r0 * LST + seg * 8] = v0;
        *(ushort8v*)&VT[0][(r0 + 32) * LST + seg * 8] = v1;
    }
    __syncthreads();   // covers staging, gsl, tile list

    int pb = 0;
    for (int i = 0; i < nt; ++i) {
        const int cb = i & 1;
        const bool pf = (i + 1 < nt);
        ushort8v k0, k1, v0, v1;
        if (pf) {   // issue next tile's global loads (land in regs; used after compute)
            int bid2 = tBid[i + 1], kb2 = tKb[i + 1];
            const unsigned short *kp, *vp;
            int vs;
            if (bid2 < 2) { kp = kbh + (size_t)kb2 * HSc; vp = vbh + kb2; vs = Tc; }
            else          { kp = krep16 + (size_t)bh * 4096;
                            vp = vcmpT16 + (size_t)bh * 4096; vs = 64; }
            k0 = *(const ushort8v*)(kp + (size_t)r0 * HSc + seg * 8);
            k1 = *(const ushort8v*)(kp + (size_t)(r0 + 32) * HSc + seg * 8);
            v0 = *(const ushort8v*)(vp + (size_t)r0 * vs + seg * 8);
            v1 = *(const ushort8v*)(vp + (size_t)(r0 + 32) * vs + seg * 8);
        }
        int bid = tBid[i];
        if (bid != pb) {   // block-uniform branch transition: merge + reset
            #pragma unroll
            for (int r = 0; r < 4; ++r) {
                float inv = gsl[pb * 64 + wq + quad * 4 + r] / o5[r];
                #pragma unroll
                for (int dt = 0; dt < 4; ++dt) { macc[dt][r] += inv * o[dt][r]; o[dt][r] = 0.f; }
                o5[r] = 0.f;
            }
            pb = bid;
        }
        attn_tile3(tP0[i], tWl[i], tKl[i], qg0, KH[cb], VT[cb], Ph,
                   aq0, aq1, ones, wq, l16, quad, o, o5);
        if (pf) {   // write prefetched tile into the other buffer
            *(ushort8v*)&KH[cb ^ 1][r0 * LST + seg * 8] = k0;
            *(ushort8v*)&KH[cb ^ 1][(r0 + 32) * LST + seg * 8] = k1;
            *(ushort8v*)&VT[cb ^ 1][r0 * LST + seg * 8] = v0;
            *(ushort8v*)&VT[cb ^ 1][(r0 + 32) * LST + seg * 8] = v1;
        }
        __syncthreads();
    }
    // final merge (pb == 2)
    #pragma unroll
    for (int r = 0; r < 4; ++r) {
        float inv = gsl[pb * 64 + wq + quad * 4 + r] / o5[r];
        #pragma unroll
        for (int dt = 0; dt < 4; ++dt) macc[dt][r] += inv * o[dt][r];
    }

    // ---- store merged fp16: row q, col h*64 + dt*16 + l16 ----
    #pragma unroll
    for (int r = 0; r < 4; ++r) {
        size_t mrow = (size_t)b * Tc + qg0 + r;
        #pragma unroll
        for (int dt = 0; dt < 4; ++dt)
            merged[mrow * Cc + h * HSc + dt * 16 + l16] = f2h(macc[dt][r]);
    }
}

// ---------------------------------------------------------------------------
extern "C" void kernel_launch(void* const* d_in, const int* in_sizes, int n_in,
                              void* d_out, int out_size, void* d_ws, size_t ws_size,
                              hipStream_t stream)
{
    const float* x  = (const float*)d_in[0];
    const float* Wq = (const float*)d_in[1];
    const float* bq = (const float*)d_in[2];
    const float* Wk = (const float*)d_in[3];
    const float* bk = (const float*)d_in[4];
    const float* Wv = (const float*)d_in[5];
    const float* bv = (const float*)d_in[6];
    const float* Wo = (const float*)d_in[7];
    const float* bo = (const float*)d_in[8];
    const float* Wg = (const float*)d_in[9];
    const float* bg = (const float*)d_in[10];
    float* out = (float*)d_out;
    float* ws  = (float*)d_ws;

    // workspace layout (float offsets)
    float* Qw   = ws + 0;                                    // 4 Mi floats
    unsigned short* Kf16 = (unsigned short*)(ws + 4194304);  // 4 Mi ushort
    unsigned short* Vf16 = (unsigned short*)(ws + 6291456);  // 4 Mi ushort
    unsigned short* Vt16 = (unsigned short*)(ws + 8388608);  // 4 Mi ushort
    unsigned short* Mgb  = (unsigned short*)(ws + 10485760); // 4 Mi ushort (fattn out)
    unsigned short* xb   = (unsigned short*)(ws + 12582912); // 4 Mi ushort
    unsigned short* WqkvT = (unsigned short*)(ws + 14680064);// 3 Mi ushort
    unsigned short* WoT   = (unsigned short*)(ws + 16252928);// 1 Mi ushort
    float* gates = ws + 16777216;   // 12288
    float* krep  = ws + 16789504;   // 65536
    unsigned short* krep16  = (unsigned short*)(ws + 16855040); // 131072 ushort
    unsigned short* vcmpT16 = (unsigned short*)(ws + 16920576); // 131072 ushort
    float* qpart = ws + 16986112;   // 65536
    int*   topidx = (int*)(ws + 17051648); // 256 ints

    // conversions
    cvt_f16_kernel<<<4096, 256, 0, stream>>>(x, xb);
    cvt_wT4_kernel<<<dim3(16, 16, 4), 256, 0, stream>>>(Wq, Wk, Wv, Wo, WqkvT, WoT);

    mfma_gemm_qkv<<<dim3(24, 32), 256, 0, stream>>>(xb, WqkvT, bq, bk, bv,
                                                    Qw, Kf16, Vf16);
    vtrans_kernel<<<dim3(Tc / 64, Bc * Hc), 256, 0, stream>>>(Vf16, Vt16);
    gates_kernel<<<Mrows / 4, 256, 0, stream>>>(x, Wg, bg, gates);
    blockstats_kernel<<<dim3(64, Bc * Hc), 64, 0, stream>>>(Kf16, Vt16, krep,
                                                            krep16, vcmpT16);
    qbar_part_kernel<<<dim3(QCH, Bc * Hc), 64, 0, stream>>>(Qw, qpart);
    topk_kernel<<<Bc * Hc, 64, 0, stream>>>(qpart, krep, topidx);
    fattn_kernel<<<dim3(Tc / 64, Bc * Hc), 256, 0, stream>>>(Qw, Kf16, Vt16,
                                                             krep16, vcmpT16,
                                                             topidx, gates, Mgb);
    mfma_gemm_kernel<<<dim3(8, 32), 256, 0, stream>>>(Mgb, WoT, bo, out);
}

// Round 10
// 290.310 us; speedup vs baseline: 1.0634x; 1.0634x over previous
//
#include <hip/hip_runtime.h>
#include <hip/hip_bf16.h>
#include <math.h>

// Problem constants
#define Bc   2
#define Tc   2048
#define Cc   1024
#define Hc   16
#define HSc  64
#define WSZ  128
#define BLKc 64
#define NBc  32
#define NSELc 8
#define Mrows (Bc*Tc)   // 4096
#define QCH  32         // qbar chunks over T
#define LST  88         // K/V LDS ushort row stride (176 B; 8 rows tile 32 banks)
#define LSTP 68         // Ph LDS ushort row stride (34 dw = +2 banks/row)
#define MAXT 12         // max tiles per fattn block (3 slide + 8 sel + 1 cmp)
#define SOFT_C 4.0f     // constant softmax shift (scores |s| << 4; exact ratio)

typedef __attribute__((ext_vector_type(8))) _Float16 half8;  // 8 fp16 in 4 VGPRs
typedef __attribute__((ext_vector_type(4))) float f32x4v;
typedef __attribute__((ext_vector_type(8))) unsigned short ushort8v;

__device__ __forceinline__ float wave_sum(float v) {
    #pragma unroll
    for (int o = 32; o; o >>= 1) v += __shfl_xor(v, o);
    return v;
}

__device__ __forceinline__ unsigned short f2h(float f) {
    _Float16 h = (_Float16)f;
    unsigned short u;
    __builtin_memcpy(&u, &h, 2);
    return u;
}
__device__ __forceinline__ float h2f(unsigned short u) {
    _Float16 h;
    __builtin_memcpy(&h, &u, 2);
    return (float)h;
}

// async global->LDS, 16B per lane; LDS dest = base + lane*16 (wave-uniform base)
__device__ __forceinline__ void gload16(const void* g, void* l) {
    __builtin_amdgcn_global_load_lds(
        (const __attribute__((address_space(1))) void*)g,
        (__attribute__((address_space(3))) void*)l, 16, 0, 0);
}

// ---------------------------------------------------------------------------
// fp32 -> fp16 (bits) elementwise. n = grid*256*4 elements exactly.
// ---------------------------------------------------------------------------
__global__ __launch_bounds__(256)
void cvt_f16_kernel(const float* __restrict__ src, unsigned short* __restrict__ dst)
{
    int i = (blockIdx.x * 256 + threadIdx.x) * 4;
    float4 v = *(const float4*)&src[i];
    ushort4 o;
    o.x = f2h(v.x); o.y = f2h(v.y); o.z = f2h(v.z); o.w = f2h(v.w);
    *(ushort4*)&dst[i] = o;
}

// ---------------------------------------------------------------------------
// 4x W (1024x1024 fp32) -> WT (N x K fp16). z<3 -> D012 (concat QKV), z==3 -> D3.
// ---------------------------------------------------------------------------
__global__ __launch_bounds__(256)
void cvt_wT4_kernel(const float* __restrict__ W0, const float* __restrict__ W1,
                    const float* __restrict__ W2, const float* __restrict__ W3,
                    unsigned short* __restrict__ D012, unsigned short* __restrict__ D3)
{
    __shared__ float tile[64][65];
    const int z = blockIdx.z;
    const float* W = (z == 0) ? W0 : (z == 1) ? W1 : (z == 2) ? W2 : W3;
    unsigned short* WT = (z < 3) ? (D012 + (size_t)z * 1024 * 1024) : D3;
    const int n0 = blockIdx.x * 64, k0 = blockIdx.y * 64;
    const int tid = threadIdx.x;
    #pragma unroll
    for (int it = 0; it < 16; ++it) {
        int lin = tid + it * 256;
        int r = lin >> 6, c = lin & 63;          // r = k, c = n
        tile[r][c] = W[(size_t)(k0 + r) * 1024 + n0 + c];
    }
    __syncthreads();
    #pragma unroll
    for (int it = 0; it < 16; ++it) {
        int lin = tid + it * 256;
        int n = lin >> 6, k = lin & 63;
        WT[(size_t)(n0 + n) * 1024 + k0 + k] = f2h(tile[k][n]);
    }
}

// ---------------------------------------------------------------------------
// Fused QKV fp16 MFMA GEMM, BK=32 (reverted: BK=64 regressed, R9/m132).
// Q -> fp16 pre-scaled x0.125 (b,h,t,d); K -> fp16; V -> fp16 row-major.
// ---------------------------------------------------------------------------
__global__ __launch_bounds__(256)
void mfma_gemm_qkv(const unsigned short* __restrict__ A,
                   const unsigned short* __restrict__ BT,
                   const float* __restrict__ bq, const float* __restrict__ bk,
                   const float* __restrict__ bv,
                   unsigned short* __restrict__ Qh, unsigned short* __restrict__ Kf,
                   unsigned short* __restrict__ Vf)
{
    constexpr int K = 1024;
    __shared__ unsigned short As[4 * 128 * 8];   // 8 KB
    __shared__ unsigned short Bs[4 * 128 * 8];   // 8 KB
    const int tid  = threadIdx.x;
    const int lane = tid & 63;
    const int wid  = tid >> 6;
    const int m0 = blockIdx.y * 128, n0 = blockIdx.x * 128;
    const int wm = (wid >> 1) * 64, wn = (wid & 1) * 64;

    f32x4v acc[4][4];
    #pragma unroll
    for (int i = 0; i < 4; ++i)
        #pragma unroll
        for (int j = 0; j < 4; ++j)
            acc[i][j] = (f32x4v){0.f, 0.f, 0.f, 0.f};

    const int kq_r = lane >> 4;
    const int r16  = lane & 15;

    for (int k0 = 0; k0 < K; k0 += 32) {
        __syncthreads();
        #pragma unroll
        for (int it = 0; it < 2; ++it) {
            int cell = wid * 64 + it * 256 + lane;    // 0..511
            int kq = cell >> 7, row = cell & 127;
            gload16(A  + (size_t)(m0 + row) * K + k0 + kq * 8,
                    As + (size_t)(wid * 64 + it * 256) * 8);
            gload16(BT + (size_t)(n0 + row) * K + k0 + kq * 8,
                    Bs + (size_t)(wid * 64 + it * 256) * 8);
        }
        __syncthreads();

        half8 af[4], bf[4];
        #pragma unroll
        for (int i = 0; i < 4; ++i)
            af[i] = *(const half8*)&As[(size_t)(kq_r * 128 + wm + i * 16 + r16) * 8];
        #pragma unroll
        for (int j = 0; j < 4; ++j)
            bf[j] = *(const half8*)&Bs[(size_t)(kq_r * 128 + wn + j * 16 + r16) * 8];
        #pragma unroll
        for (int i = 0; i < 4; ++i)
            #pragma unroll
            for (int j = 0; j < 4; ++j)
                acc[i][j] = __builtin_amdgcn_mfma_f32_16x16x32_f16(af[i], bf[j], acc[i][j], 0, 0, 0);
    }

    const int which = n0 >> 10;   // 0=Q 1=K 2=V (block-uniform)
    const float* bias = (which == 0) ? bq : ((which == 1) ? bk : bv);

    #pragma unroll
    for (int i = 0; i < 4; ++i) {
        int mbase = m0 + wm + i * 16 + (lane >> 4) * 4;
        #pragma unroll
        for (int j = 0; j < 4; ++j) {
            int n = n0 + wn + j * 16 + (lane & 15);
            int nn = n & 1023;
            float bvv = bias[nn];
            int h = nn >> 6, d = nn & 63;
            #pragma unroll
            for (int r = 0; r < 4; ++r) {
                int m = mbase + r;
                int b = m >> 11, t = m & 2047;
                float v = acc[i][j][r] + bvv;
                size_t idx = (((size_t)(b * Hc + h) * Tc) + t) * HSc + d;
                if (which == 0)      Qh[idx] = f2h(v * 0.125f);
                else if (which == 1) Kf[idx] = f2h(v);
                else                 Vf[idx] = f2h(v);
            }
        }
    }
}

// ---------------------------------------------------------------------------
// fp16 MFMA GEMM (row-major fp32 out), BK=32: final projection.
// ---------------------------------------------------------------------------
__global__ __launch_bounds__(256)
void mfma_gemm_kernel(const unsigned short* __restrict__ A,
                      const unsigned short* __restrict__ BT,
                      const float* __restrict__ bias,
                      float* __restrict__ Y)
{
    constexpr int K = 1024;
    __shared__ unsigned short As[4 * 128 * 8];
    __shared__ unsigned short Bs[4 * 128 * 8];
    const int tid  = threadIdx.x;
    const int lane = tid & 63;
    const int wid  = tid >> 6;
    const int m0 = blockIdx.y * 128, n0 = blockIdx.x * 128;
    const int wm = (wid >> 1) * 64, wn = (wid & 1) * 64;

    f32x4v acc[4][4];
    #pragma unroll
    for (int i = 0; i < 4; ++i)
        #pragma unroll
        for (int j = 0; j < 4; ++j)
            acc[i][j] = (f32x4v){0.f, 0.f, 0.f, 0.f};

    const int kq_r = lane >> 4;
    const int r16  = lane & 15;

    for (int k0 = 0; k0 < K; k0 += 32) {
        __syncthreads();
        #pragma unroll
        for (int it = 0; it < 2; ++it) {
            int cell = wid * 64 + it * 256 + lane;
            int kq = cell >> 7, row = cell & 127;
            gload16(A  + (size_t)(m0 + row) * K + k0 + kq * 8,
                    As + (size_t)(wid * 64 + it * 256) * 8);
            gload16(BT + (size_t)(n0 + row) * K + k0 + kq * 8,
                    Bs + (size_t)(wid * 64 + it * 256) * 8);
        }
        __syncthreads();

        half8 af[4], bf[4];
        #pragma unroll
        for (int i = 0; i < 4; ++i)
            af[i] = *(const half8*)&As[(size_t)(kq_r * 128 + wm + i * 16 + r16) * 8];
        #pragma unroll
        for (int j = 0; j < 4; ++j)
            bf[j] = *(const half8*)&Bs[(size_t)(kq_r * 128 + wn + j * 16 + r16) * 8];
        #pragma unroll
        for (int i = 0; i < 4; ++i)
            #pragma unroll
            for (int j = 0; j < 4; ++j)
                acc[i][j] = __builtin_amdgcn_mfma_f32_16x16x32_f16(af[i], bf[j], acc[i][j], 0, 0, 0);
    }

    #pragma unroll
    for (int i = 0; i < 4; ++i) {
        int mbase = m0 + wm + i * 16 + (lane >> 4) * 4;
        #pragma unroll
        for (int j = 0; j < 4; ++j) {
            int n = n0 + wn + j * 16 + (lane & 15);
            float bv = bias[n];
            #pragma unroll
            for (int r = 0; r < 4; ++r)
                Y[(size_t)(mbase + r) * 1024 + n] = acc[i][j][r] + bv;
        }
    }
}

// ---------------------------------------------------------------------------
// V (bh,t,d) fp16 -> Vt (bh,d,t) fp16. grid (Tc/64, B*H), 256 thr.
// ---------------------------------------------------------------------------
__global__ __launch_bounds__(256)
void vtrans_kernel(const unsigned short* __restrict__ Vf, unsigned short* __restrict__ Vt)
{
    __shared__ unsigned short tile[64][65];
    const int t0 = blockIdx.x * 64, bh = blockIdx.y;
    const int tid = threadIdx.x;
    const int c4 = (tid & 15) * 4, r = tid >> 4;   // 16 rows/iter
    const unsigned short* src = Vf + ((size_t)bh * Tc + t0) * HSc;
    #pragma unroll
    for (int it = 0; it < 4; ++it) {
        int tt = r + it * 16;
        *(ushort4*)&tile[tt][c4] = *(const ushort4*)&src[(size_t)tt * HSc + c4];
    }
    __syncthreads();
    unsigned short* dst = Vt + (size_t)bh * HSc * Tc + t0;
    #pragma unroll
    for (int it = 0; it < 4; ++it) {
        int d = r + it * 16;
        ushort4 o;
        o.x = tile[c4 + 0][d]; o.y = tile[c4 + 1][d];
        o.z = tile[c4 + 2][d]; o.w = tile[c4 + 3][d];
        *(ushort4*)&dst[(size_t)d * Tc + c4] = o;
    }
}

// ---------------------------------------------------------------------------
// Gates: one wave per row (4 rows/block), float4 loads.
// ---------------------------------------------------------------------------
__global__ __launch_bounds__(256)
void gates_kernel(const float* __restrict__ x, const float* __restrict__ Wg,
                  const float* __restrict__ bg, float* __restrict__ gates)
{
    const int row  = blockIdx.x * 4 + (threadIdx.x >> 6);
    const int lane = threadIdx.x & 63;
    const float* xr = x + (size_t)row * Cc;
    float p0 = 0, p1 = 0, p2 = 0;
    #pragma unroll
    for (int it = 0; it < 4; ++it) {
        int k4 = lane * 4 + it * 256;
        float4 xv = *(const float4*)&xr[k4];
        float4 w0 = *(const float4*)&Wg[k4 * 3];
        float4 w1 = *(const float4*)&Wg[k4 * 3 + 4];
        float4 w2 = *(const float4*)&Wg[k4 * 3 + 8];
        p0 += xv.x * w0.x + xv.y * w0.w + xv.z * w1.z + xv.w * w2.y;
        p1 += xv.x * w0.y + xv.y * w1.x + xv.z * w1.w + xv.w * w2.z;
        p2 += xv.x * w0.z + xv.y * w1.y + xv.z * w2.x + xv.w * w2.w;
    }
    p0 = wave_sum(p0); p1 = wave_sum(p1); p2 = wave_sum(p2);
    if (lane == 0) {
        p0 += bg[0]; p1 += bg[1]; p2 += bg[2];
        float m = fmaxf(p0, fmaxf(p1, p2));
        float e0 = expf(p0 - m), e1 = expf(p1 - m), e2 = expf(p2 - m);
        float s = e0 + e1 + e2;
        gates[row * 3 + 0] = e0 / s;
        gates[row * 3 + 1] = e1 / s;
        gates[row * 3 + 2] = e2 / s;
    }
}

// ---------------------------------------------------------------------------
// Per-block K/V means -> fp32 krep (topk) + zero-padded fp16 staging buffers.
// ---------------------------------------------------------------------------
__global__ __launch_bounds__(64)
void blockstats_kernel(const unsigned short* __restrict__ Kf,
                       const unsigned short* __restrict__ Vt,
                       float* __restrict__ krep,
                       unsigned short* __restrict__ krep16,
                       unsigned short* __restrict__ vcmpT16)
{
    int nb = blockIdx.x, bh = blockIdx.y, d = threadIdx.x;
    if (nb < NBc) {
        const unsigned short* kp = Kf + ((size_t)bh * Tc + nb * BLKc) * HSc + d;
        const unsigned short* vp = Vt + ((size_t)bh * HSc + d) * Tc + nb * BLKc;
        float sk = 0, sv = 0;
        #pragma unroll 8
        for (int j = 0; j < BLKc; j++) {
            sk += h2f(kp[(size_t)j * HSc]);
            sv += h2f(vp[j]);
        }
        float km = sk * (1.0f / BLKc), vm = sv * (1.0f / BLKc);
        krep[((size_t)bh * NBc + nb) * HSc + d] = km;
        krep16[(size_t)bh * 4096 + nb * 64 + d] = f2h(km);
        vcmpT16[(size_t)bh * 4096 + d * 64 + nb] = f2h(vm);
    } else {
        krep16[(size_t)bh * 4096 + nb * 64 + d] = 0;
        vcmpT16[(size_t)bh * 4096 + d * 64 + nb] = 0;
    }
}

// ---------------------------------------------------------------------------
// qbar partials from fp16 Q (pre-scaled x0.125; scale cancels in qn).
// ---------------------------------------------------------------------------
__global__ __launch_bounds__(64)
void qbar_part_kernel(const unsigned short* __restrict__ Qh, float* __restrict__ qpart)
{
    int ch = blockIdx.x, bh = blockIdx.y, d = threadIdx.x;
    int t0 = ch * (Tc / QCH);
    float acc = 0.0f;
    for (int it = 0; it < Tc / QCH; it++) {
        float v = h2f(Qh[((size_t)bh * Tc + t0 + it) * HSc + d]);
        float sq = wave_sum(v * v);
        float nrm = fmaxf(sqrtf(sq), 1e-8f);
        acc += v / nrm;
    }
    qpart[((size_t)bh * QCH + ch) * HSc + d] = acc;
}

// ---------------------------------------------------------------------------
// Selection scores + top-8 (descending, ties -> lower index)
// ---------------------------------------------------------------------------
__global__ __launch_bounds__(64)
void topk_kernel(const float* __restrict__ qpart, const float* __restrict__ krep,
                 int* __restrict__ topidx)
{
    int bh = blockIdx.x, lane = threadIdx.x;
    __shared__ float sc[NBc];
    __shared__ float qbs[HSc];
    float qa = 0.0f;
    #pragma unroll
    for (int c = 0; c < QCH; c++)
        qa += qpart[((size_t)bh * QCH + c) * HSc + lane];
    qbs[lane] = qa * (1.0f / Tc);
    __syncthreads();
    if (lane < NBc) {
        float dot = 0, nk = 0;
        for (int d = 0; d < HSc; d++) {
            float kv = krep[((size_t)bh * NBc + lane) * HSc + d];
            nk += kv * kv;
            dot += qbs[d] * kv;
        }
        sc[lane] = dot / fmaxf(sqrtf(nk), 1e-8f);
    }
    __syncthreads();
    if (lane == 0) {
        for (int s = 0; s < NSELc; s++) {
            int best = 0; float bv = sc[0];
            for (int n = 1; n < NBc; n++)
                if (sc[n] > bv) { bv = sc[n]; best = n; }
            topidx[bh * NSELc + s] = best;
            sc[best] = -INFINITY;
        }
    }
}

// ===========================================================================
// MFMA flash attention, constant-shift softmax, ones-MFMA row sums,
// pipelined flat tile loop, dbuf staging, fp16 in/out.
// ===========================================================================
__device__ __forceinline__ void attn_tile3(
    int p0, int wlim, int klim, int qg0,
    const unsigned short* __restrict__ Kh, const unsigned short* __restrict__ Vt,
    unsigned short* __restrict__ Ph,
    half8 aq0, half8 aq1, half8 ones, int wq, int l16, int quad,
    f32x4v o[4], f32x4v& o5)
{
    // ---- QK^T: 8 MFMAs ----
    f32x4v s[4];
    #pragma unroll
    for (int t = 0; t < 4; ++t) {
        f32x4v sa = (f32x4v){0.f, 0.f, 0.f, 0.f};
        half8 b0 = *(const half8*)&Kh[(t * 16 + l16) * LST + quad * 8];
        half8 b1 = *(const half8*)&Kh[(t * 16 + l16) * LST + 32 + quad * 8];
        sa = __builtin_amdgcn_mfma_f32_16x16x32_f16(aq0, b0, sa, 0, 0, 0);
        sa = __builtin_amdgcn_mfma_f32_16x16x32_f16(aq1, b1, sa, 0, 0, 0);
        s[t] = sa;
    }

    // ---- mask + P = exp(s - C) -> Ph (wave-private rows) ----
    #pragma unroll
    for (int t = 0; t < 4; ++t) {
        int kk = t * 16 + l16;
        bool kok = kk < klim;
        int jt = p0 + kk;
        #pragma unroll
        for (int r = 0; r < 4; ++r) {
            int q = qg0 + r;
            bool valid = kok && (jt <= q) && (q - jt <= wlim);
            float p = valid ? __expf(s[t][r] - SOFT_C) : 0.0f;
            Ph[(wq + quad * 4 + r) * LSTP + t * 16 + l16] = f2h(p);
        }
    }

    // NO barrier: Ph write/read is same-wave (lgkmcnt-ordered)

    // ---- PV: 8 MFMAs + 2 ones-MFMAs (row sums into o5) ----
    half8 ap0 = *(const half8*)&Ph[(wq + l16) * LSTP + quad * 8];
    half8 ap1 = *(const half8*)&Ph[(wq + l16) * LSTP + 32 + quad * 8];
    o5 = __builtin_amdgcn_mfma_f32_16x16x32_f16(ap0, ones, o5, 0, 0, 0);
    o5 = __builtin_amdgcn_mfma_f32_16x16x32_f16(ap1, ones, o5, 0, 0, 0);
    #pragma unroll
    for (int dt = 0; dt < 4; ++dt) {
        half8 v0 = *(const half8*)&Vt[(dt * 16 + l16) * LST + quad * 8];
        half8 v1 = *(const half8*)&Vt[(dt * 16 + l16) * LST + 32 + quad * 8];
        o[dt] = __builtin_amdgcn_mfma_f32_16x16x32_f16(ap0, v0, o[dt], 0, 0, 0);
        o[dt] = __builtin_amdgcn_mfma_f32_16x16x32_f16(ap1, v1, o[dt], 0, 0, 0);
    }
}

__global__ __launch_bounds__(256)
void fattn_kernel(const unsigned short* __restrict__ Qh16,
                  const unsigned short* __restrict__ Kf,
                  const unsigned short* __restrict__ Vtg,
                  const unsigned short* __restrict__ krep16,
                  const unsigned short* __restrict__ vcmpT16,
                  const int* __restrict__ topidx,
                  const float* __restrict__ gates, unsigned short* __restrict__ merged)
{
    __shared__ unsigned short KH[2][64 * LST];
    __shared__ unsigned short VT[2][64 * LST];
    __shared__ unsigned short Ph[64 * LSTP];
    __shared__ float gsl[3 * 64];
    __shared__ int tKb[MAXT], tP0[MAXT], tWl[MAXT], tKl[MAXT], tBid[MAXT];

    const int qt = blockIdx.x;      // 0..31
    const int bh = blockIdx.y;      // 0..31
    const int b  = bh >> 4, h = bh & 15;
    const int tid  = threadIdx.x;
    const int wid  = tid >> 6, lane = tid & 63;
    const int l16  = lane & 15, quad = lane >> 4;
    const int q0 = qt * 64;
    const int wq = wid * 16;
    const int qg0 = q0 + wq + quad * 4;   // global q row of reg 0

    const int nslide = (qt < 2 ? qt : 2) + 1;
    const int nsel   = (qt + 1 < NSELc) ? (qt + 1) : NSELc;
    const int nt     = nslide + nsel + 1;

    // ---- Q fragments directly from global fp16 (pre-scaled), ones frag ----
    half8 aq0, aq1, ones;
    {
        const unsigned short* qrow = Qh16 + ((size_t)bh * Tc + q0 + wq + l16) * HSc;
        aq0 = *(const half8*)(qrow + quad * 8);
        aq1 = *(const half8*)(qrow + 32 + quad * 8);
        #pragma unroll
        for (int j = 0; j < 8; ++j) ones[j] = (_Float16)1.0f;
    }

    if (tid < 64) {
        size_t gb = ((size_t)b * Tc + q0 + tid) * 3;
        gsl[0 * 64 + tid] = gates[gb + 0];
        gsl[1 * 64 + tid] = gates[gb + 1];
        gsl[2 * 64 + tid] = gates[gb + 2];
    }
    // ---- build tile descriptor list ----
    if (tid < nt) {
        int i = tid, kb, p0, wl, kl, bid;
        if (i < nslide)            { int tb = q0 - (nslide - 1 - i) * 64;
                                     kb = tb; p0 = tb; wl = WSZ; kl = 64; bid = 0; }
        else if (i < nslide + nsel){ int s = i - nslide;
                                     kb = topidx[bh * NSELc + s] * BLKc;
                                     p0 = s * BLKc; wl = 1 << 30; kl = 64; bid = 1; }
        else                       { kb = 0; p0 = 0; wl = 1 << 30; kl = NBc; bid = 2; }
        tKb[i] = kb; tP0[i] = p0; tWl[i] = wl; tKl[i] = kl; tBid[i] = bid;
    }

    f32x4v o[4], macc[4];
    f32x4v o5 = (f32x4v){0.f, 0.f, 0.f, 0.f};
    #pragma unroll
    for (int dt = 0; dt < 4; ++dt) {
        o[dt]    = (f32x4v){0.f, 0.f, 0.f, 0.f};
        macc[dt] = (f32x4v){0.f, 0.f, 0.f, 0.f};
    }

    const int seg = tid & 7, r0 = tid >> 3;   // 8 segs x 32 rows
    const unsigned short* kbh = Kf  + (size_t)bh * Tc * HSc;
    const unsigned short* vbh = Vtg + (size_t)bh * HSc * Tc;

    // ---- stage tile 0 (always sliding) into buffer 0 ----
    {
        int tb0 = q0 - (nslide - 1) * 64;
        const unsigned short* kp = kbh + (size_t)tb0 * HSc;
        const unsigned short* vp = vbh + tb0;
        ushort8v k0 = *(const ushort8v*)(kp + (size_t)r0 * HSc + seg * 8);
        ushort8v k1 = *(const ushort8v*)(kp + (size_t)(r0 + 32) * HSc + seg * 8);
        ushort8v v0 = *(const ushort8v*)(vp + (size_t)r0 * Tc + seg * 8);
        ushort8v v1 = *(const ushort8v*)(vp + (size_t)(r0 + 32) * Tc + seg * 8);
        *(ushort8v*)&KH[0][r0 * LST + seg * 8] = k0;
        *(ushort8v*)&KH[0][(r0 + 32) * LST + seg * 8] = k1;
        *(ushort8v*)&VT[0][r0 * LST + seg * 8] = v0;
        *(ushort8v*)&VT[0][(r0 + 32) * LST + seg * 8] = v1;
    }
    __syncthreads();   // covers staging, gsl, tile list

    int pb = 0;
    for (int i = 0; i < nt; ++i) {
        const int cb = i & 1;
        const bool pf = (i + 1 < nt);
        ushort8v k0, k1, v0, v1;
        if (pf) {   // issue next tile's global loads (land in regs; used after compute)
            int bid2 = tBid[i + 1], kb2 = tKb[i + 1];
            const unsigned short *kp, *vp;
            int vs;
            if (bid2 < 2) { kp = kbh + (size_t)kb2 * HSc; vp = vbh + kb2; vs = Tc; }
            else          { kp = krep16 + (size_t)bh * 4096;
                            vp = vcmpT16 + (size_t)bh * 4096; vs = 64; }
            k0 = *(const ushort8v*)(kp + (size_t)r0 * HSc + seg * 8);
            k1 = *(const ushort8v*)(kp + (size_t)(r0 + 32) * HSc + seg * 8);
            v0 = *(const ushort8v*)(vp + (size_t)r0 * vs + seg * 8);
            v1 = *(const ushort8v*)(vp + (size_t)(r0 + 32) * vs + seg * 8);
        }
        int bid = tBid[i];
        if (bid != pb) {   // block-uniform branch transition: merge + reset
            #pragma unroll
            for (int r = 0; r < 4; ++r) {
                float inv = gsl[pb * 64 + wq + quad * 4 + r] / o5[r];
                #pragma unroll
                for (int dt = 0; dt < 4; ++dt) { macc[dt][r] += inv * o[dt][r]; o[dt][r] = 0.f; }
                o5[r] = 0.f;
            }
            pb = bid;
        }
        attn_tile3(tP0[i], tWl[i], tKl[i], qg0, KH[cb], VT[cb], Ph,
                   aq0, aq1, ones, wq, l16, quad, o, o5);
        if (pf) {   // write prefetched tile into the other buffer
            *(ushort8v*)&KH[cb ^ 1][r0 * LST + seg * 8] = k0;
            *(ushort8v*)&KH[cb ^ 1][(r0 + 32) * LST + seg * 8] = k1;
            *(ushort8v*)&VT[cb ^ 1][r0 * LST + seg * 8] = v0;
            *(ushort8v*)&VT[cb ^ 1][(r0 + 32) * LST + seg * 8] = v1;
        }
        __syncthreads();
    }
    // final merge (pb == 2)
    #pragma unroll
    for (int r = 0; r < 4; ++r) {
        float inv = gsl[pb * 64 + wq + quad * 4 + r] / o5[r];
        #pragma unroll
        for (int dt = 0; dt < 4; ++dt) macc[dt][r] += inv * o[dt][r];
    }

    // ---- store merged fp16: row q, col h*64 + dt*16 + l16 ----
    #pragma unroll
    for (int r = 0; r < 4; ++r) {
        size_t mrow = (size_t)b * Tc + qg0 + r;
        #pragma unroll
        for (int dt = 0; dt < 4; ++dt)
            merged[mrow * Cc + h * HSc + dt * 16 + l16] = f2h(macc[dt][r]);
    }
}

// ---------------------------------------------------------------------------
extern "C" void kernel_launch(void* const* d_in, const int* in_sizes, int n_in,
                              void* d_out, int out_size, void* d_ws, size_t ws_size,
                              hipStream_t stream)
{
    const float* x  = (const float*)d_in[0];
    const float* Wq = (const float*)d_in[1];
    const float* bq = (const float*)d_in[2];
    const float* Wk = (const float*)d_in[3];
    const float* bk = (const float*)d_in[4];
    const float* Wv = (const float*)d_in[5];
    const float* bv = (const float*)d_in[6];
    const float* Wo = (const float*)d_in[7];
    const float* bo = (const float*)d_in[8];
    const float* Wg = (const float*)d_in[9];
    const float* bg = (const float*)d_in[10];
    float* out = (float*)d_out;
    float* ws  = (float*)d_ws;

    // workspace layout (float offsets)
    unsigned short* Qh16 = (unsigned short*)(ws + 0);        // 4 Mi ushort
    unsigned short* Kf16 = (unsigned short*)(ws + 2097152);  // 4 Mi ushort
    unsigned short* Vf16 = (unsigned short*)(ws + 4194304);  // 4 Mi ushort
    unsigned short* Vt16 = (unsigned short*)(ws + 6291456);  // 4 Mi ushort
    unsigned short* Mgb  = (unsigned short*)(ws + 8388608);  // 4 Mi ushort
    unsigned short* xb   = (unsigned short*)(ws + 10485760); // 4 Mi ushort
    unsigned short* WqkvT = (unsigned short*)(ws + 12582912);// 3 Mi ushort
    unsigned short* WoT   = (unsigned short*)(ws + 14155776);// 1 Mi ushort
    float* gates = ws + 14680064;   // 12288
    float* krep  = ws + 14692352;   // 65536
    unsigned short* krep16  = (unsigned short*)(ws + 14757888); // 131072 ushort
    unsigned short* vcmpT16 = (unsigned short*)(ws + 14823424); // 131072 ushort
    float* qpart = ws + 14888960;   // 65536
    int*   topidx = (int*)(ws + 14954496); // 256 ints

    // conversions
    cvt_f16_kernel<<<4096, 256, 0, stream>>>(x, xb);
    cvt_wT4_kernel<<<dim3(16, 16, 4), 256, 0, stream>>>(Wq, Wk, Wv, Wo, WqkvT, WoT);

    mfma_gemm_qkv<<<dim3(24, 32), 256, 0, stream>>>(xb, WqkvT, bq, bk, bv,
                                                    Qh16, Kf16, Vf16);
    vtrans_kernel<<<dim3(Tc / 64, Bc * Hc), 256, 0, stream>>>(Vf16, Vt16);
    gates_kernel<<<Mrows / 4, 256, 0, stream>>>(x, Wg, bg, gates);
    blockstats_kernel<<<dim3(64, Bc * Hc), 64, 0, stream>>>(Kf16, Vt16, krep,
                                                            krep16, vcmpT16);
    qbar_part_kernel<<<dim3(QCH, Bc * Hc), 64, 0, stream>>>(Qh16, qpart);
    topk_kernel<<<Bc * Hc, 64, 0, stream>>>(qpart, krep, topidx);
    fattn_kernel<<<dim3(Tc / 64, Bc * Hc), 256, 0, stream>>>(Qh16, Kf16, Vt16,
                                                             krep16, vcmpT16,
                                                             topidx, gates, Mgb);
    mfma_gemm_kernel<<<dim3(8, 32), 256, 0, stream>>>(Mgb, WoT, bo, out);
}

// Round 11
// 262.003 us; speedup vs baseline: 1.1783x; 1.1080x over previous
//
#include <hip/hip_runtime.h>
#include <hip/hip_bf16.h>
#include <math.h>

// Problem constants
#define Bc   2
#define Tc   2048
#define Cc   1024
#define Hc   16
#define HSc  64
#define WSZ  128
#define BLKc 64
#define NBc  32
#define NSELc 8
#define Mrows (Bc*Tc)   // 4096
#define QCH  32         // qbar chunks over T
#define LST  88         // K/V LDS ushort row stride (176 B; 8 rows tile 32 banks)
#define LSTP 68         // Ph LDS ushort row stride (34 dw = +2 banks/row)
#define MAXT 12         // max tiles per fattn block (3 slide + 8 sel + 1 cmp)
#define SOFT_C 4.0f     // constant softmax shift (scores |s| << 4; exact ratio)

typedef __attribute__((ext_vector_type(8))) _Float16 half8;  // 8 fp16 in 4 VGPRs
typedef __attribute__((ext_vector_type(4))) float f32x4v;
typedef __attribute__((ext_vector_type(8))) unsigned short ushort8v;

__device__ __forceinline__ float wave_sum(float v) {
    #pragma unroll
    for (int o = 32; o; o >>= 1) v += __shfl_xor(v, o);
    return v;
}

__device__ __forceinline__ unsigned short f2h(float f) {
    _Float16 h = (_Float16)f;
    unsigned short u;
    __builtin_memcpy(&u, &h, 2);
    return u;
}
__device__ __forceinline__ float h2f(unsigned short u) {
    _Float16 h;
    __builtin_memcpy(&h, &u, 2);
    return (float)h;
}

// async global->LDS, 16B per lane; LDS dest = base + lane*16 (wave-uniform base)
__device__ __forceinline__ void gload16(const void* g, void* l) {
    __builtin_amdgcn_global_load_lds(
        (const __attribute__((address_space(1))) void*)g,
        (__attribute__((address_space(3))) void*)l, 16, 0, 0);
}

// ---------------------------------------------------------------------------
// Merged: blocks <4096: fp32->fp16 cvt of x; blocks >=4096: gates rows.
// ---------------------------------------------------------------------------
__global__ __launch_bounds__(256)
void cvt_gates_kernel(const float* __restrict__ x, unsigned short* __restrict__ xb,
                      const float* __restrict__ Wg, const float* __restrict__ bg,
                      float* __restrict__ gates)
{
    if (blockIdx.x < 4096) {
        int i = (blockIdx.x * 256 + threadIdx.x) * 4;
        float4 v = *(const float4*)&x[i];
        ushort4 o;
        o.x = f2h(v.x); o.y = f2h(v.y); o.z = f2h(v.z); o.w = f2h(v.w);
        *(ushort4*)&xb[i] = o;
        return;
    }
    const int row  = (blockIdx.x - 4096) * 4 + (threadIdx.x >> 6);
    const int lane = threadIdx.x & 63;
    const float* xr = x + (size_t)row * Cc;
    float p0 = 0, p1 = 0, p2 = 0;
    #pragma unroll
    for (int it = 0; it < 4; ++it) {
        int k4 = lane * 4 + it * 256;
        float4 xv = *(const float4*)&xr[k4];
        float4 w0 = *(const float4*)&Wg[k4 * 3];
        float4 w1 = *(const float4*)&Wg[k4 * 3 + 4];
        float4 w2 = *(const float4*)&Wg[k4 * 3 + 8];
        p0 += xv.x * w0.x + xv.y * w0.w + xv.z * w1.z + xv.w * w2.y;
        p1 += xv.x * w0.y + xv.y * w1.x + xv.z * w1.w + xv.w * w2.z;
        p2 += xv.x * w0.z + xv.y * w1.y + xv.z * w2.x + xv.w * w2.w;
    }
    p0 = wave_sum(p0); p1 = wave_sum(p1); p2 = wave_sum(p2);
    if (lane == 0) {
        p0 += bg[0]; p1 += bg[1]; p2 += bg[2];
        float m = fmaxf(p0, fmaxf(p1, p2));
        float e0 = expf(p0 - m), e1 = expf(p1 - m), e2 = expf(p2 - m);
        float s = e0 + e1 + e2;
        gates[row * 3 + 0] = e0 / s;
        gates[row * 3 + 1] = e1 / s;
        gates[row * 3 + 2] = e2 / s;
    }
}

// ---------------------------------------------------------------------------
// 4x W (1024x1024 fp32) -> WT (N x K fp16). z<3 -> D012 (concat QKV), z==3 -> D3.
// ---------------------------------------------------------------------------
__global__ __launch_bounds__(256)
void cvt_wT4_kernel(const float* __restrict__ W0, const float* __restrict__ W1,
                    const float* __restrict__ W2, const float* __restrict__ W3,
                    unsigned short* __restrict__ D012, unsigned short* __restrict__ D3)
{
    __shared__ float tile[64][65];
    const int z = blockIdx.z;
    const float* W = (z == 0) ? W0 : (z == 1) ? W1 : (z == 2) ? W2 : W3;
    unsigned short* WT = (z < 3) ? (D012 + (size_t)z * 1024 * 1024) : D3;
    const int n0 = blockIdx.x * 64, k0 = blockIdx.y * 64;
    const int tid = threadIdx.x;
    #pragma unroll
    for (int it = 0; it < 16; ++it) {
        int lin = tid + it * 256;
        int r = lin >> 6, c = lin & 63;          // r = k, c = n
        tile[r][c] = W[(size_t)(k0 + r) * 1024 + n0 + c];
    }
    __syncthreads();
    #pragma unroll
    for (int it = 0; it < 16; ++it) {
        int lin = tid + it * 256;
        int n = lin >> 6, k = lin & 63;
        WT[(size_t)(n0 + n) * 1024 + k0 + k] = f2h(tile[k][n]);
    }
}

// ---------------------------------------------------------------------------
// Fused QKV fp16 MFMA GEMM, BK=32 (BK=64 regressed, R9/m132).
// Q -> fp16 pre-scaled x0.125 (b,h,t,d); K -> fp16; V -> fp16 row-major.
// ---------------------------------------------------------------------------
__global__ __launch_bounds__(256)
void mfma_gemm_qkv(const unsigned short* __restrict__ A,
                   const unsigned short* __restrict__ BT,
                   const float* __restrict__ bq, const float* __restrict__ bk,
                   const float* __restrict__ bv,
                   unsigned short* __restrict__ Qh, unsigned short* __restrict__ Kf,
                   unsigned short* __restrict__ Vf)
{
    constexpr int K = 1024;
    __shared__ unsigned short As[4 * 128 * 8];   // 8 KB
    __shared__ unsigned short Bs[4 * 128 * 8];   // 8 KB
    const int tid  = threadIdx.x;
    const int lane = tid & 63;
    const int wid  = tid >> 6;
    const int m0 = blockIdx.y * 128, n0 = blockIdx.x * 128;
    const int wm = (wid >> 1) * 64, wn = (wid & 1) * 64;

    f32x4v acc[4][4];
    #pragma unroll
    for (int i = 0; i < 4; ++i)
        #pragma unroll
        for (int j = 0; j < 4; ++j)
            acc[i][j] = (f32x4v){0.f, 0.f, 0.f, 0.f};

    const int kq_r = lane >> 4;
    const int r16  = lane & 15;

    for (int k0 = 0; k0 < K; k0 += 32) {
        __syncthreads();
        #pragma unroll
        for (int it = 0; it < 2; ++it) {
            int cell = wid * 64 + it * 256 + lane;    // 0..511
            int kq = cell >> 7, row = cell & 127;
            gload16(A  + (size_t)(m0 + row) * K + k0 + kq * 8,
                    As + (size_t)(wid * 64 + it * 256) * 8);
            gload16(BT + (size_t)(n0 + row) * K + k0 + kq * 8,
                    Bs + (size_t)(wid * 64 + it * 256) * 8);
        }
        __syncthreads();

        half8 af[4], bf[4];
        #pragma unroll
        for (int i = 0; i < 4; ++i)
            af[i] = *(const half8*)&As[(size_t)(kq_r * 128 + wm + i * 16 + r16) * 8];
        #pragma unroll
        for (int j = 0; j < 4; ++j)
            bf[j] = *(const half8*)&Bs[(size_t)(kq_r * 128 + wn + j * 16 + r16) * 8];
        #pragma unroll
        for (int i = 0; i < 4; ++i)
            #pragma unroll
            for (int j = 0; j < 4; ++j)
                acc[i][j] = __builtin_amdgcn_mfma_f32_16x16x32_f16(af[i], bf[j], acc[i][j], 0, 0, 0);
    }

    const int which = n0 >> 10;   // 0=Q 1=K 2=V (block-uniform)
    const float* bias = (which == 0) ? bq : ((which == 1) ? bk : bv);

    #pragma unroll
    for (int i = 0; i < 4; ++i) {
        int mbase = m0 + wm + i * 16 + (lane >> 4) * 4;
        #pragma unroll
        for (int j = 0; j < 4; ++j) {
            int n = n0 + wn + j * 16 + (lane & 15);
            int nn = n & 1023;
            float bvv = bias[nn];
            int h = nn >> 6, d = nn & 63;
            #pragma unroll
            for (int r = 0; r < 4; ++r) {
                int m = mbase + r;
                int b = m >> 11, t = m & 2047;
                float v = acc[i][j][r] + bvv;
                size_t idx = (((size_t)(b * Hc + h) * Tc) + t) * HSc + d;
                if (which == 0)      Qh[idx] = f2h(v * 0.125f);
                else if (which == 1) Kf[idx] = f2h(v);
                else                 Vf[idx] = f2h(v);
            }
        }
    }
}

// ---------------------------------------------------------------------------
// fp16 MFMA GEMM, 64x128 tile (512 blocks = 2/CU), fp32 out: final projection.
// ---------------------------------------------------------------------------
__global__ __launch_bounds__(256)
void mfma_gemm_kernel(const unsigned short* __restrict__ A,
                      const unsigned short* __restrict__ BT,
                      const float* __restrict__ bias,
                      float* __restrict__ Y)
{
    constexpr int K = 1024;
    __shared__ unsigned short As[4 * 64 * 8];    // 4 KB
    __shared__ unsigned short Bs[4 * 128 * 8];   // 8 KB
    const int tid  = threadIdx.x;
    const int lane = tid & 63;
    const int wid  = tid >> 6;
    const int m0 = blockIdx.y * 64, n0 = blockIdx.x * 128;
    const int wm = (wid >> 1) * 32, wn = (wid & 1) * 64;

    f32x4v acc[2][4];
    #pragma unroll
    for (int i = 0; i < 2; ++i)
        #pragma unroll
        for (int j = 0; j < 4; ++j)
            acc[i][j] = (f32x4v){0.f, 0.f, 0.f, 0.f};

    const int kq_r = lane >> 4;
    const int r16  = lane & 15;

    for (int k0 = 0; k0 < K; k0 += 32) {
        __syncthreads();
        // A: 256 cells (kq = wid, row = lane)
        gload16(A + (size_t)(m0 + lane) * K + k0 + wid * 8,
                As + (size_t)(wid * 64) * 8);
        // B: 512 cells
        #pragma unroll
        for (int it = 0; it < 2; ++it) {
            int cell = wid * 64 + it * 256 + lane;
            int kq = cell >> 7, row = cell & 127;
            gload16(BT + (size_t)(n0 + row) * K + k0 + kq * 8,
                    Bs + (size_t)(wid * 64 + it * 256) * 8);
        }
        __syncthreads();

        half8 af[2], bf[4];
        #pragma unroll
        for (int i = 0; i < 2; ++i)
            af[i] = *(const half8*)&As[(size_t)(kq_r * 64 + wm + i * 16 + r16) * 8];
        #pragma unroll
        for (int j = 0; j < 4; ++j)
            bf[j] = *(const half8*)&Bs[(size_t)(kq_r * 128 + wn + j * 16 + r16) * 8];
        #pragma unroll
        for (int i = 0; i < 2; ++i)
            #pragma unroll
            for (int j = 0; j < 4; ++j)
                acc[i][j] = __builtin_amdgcn_mfma_f32_16x16x32_f16(af[i], bf[j], acc[i][j], 0, 0, 0);
    }

    #pragma unroll
    for (int i = 0; i < 2; ++i) {
        int mbase = m0 + wm + i * 16 + (lane >> 4) * 4;
        #pragma unroll
        for (int j = 0; j < 4; ++j) {
            int n = n0 + wn + j * 16 + (lane & 15);
            float bv = bias[n];
            #pragma unroll
            for (int r = 0; r < 4; ++r)
                Y[(size_t)(mbase + r) * 1024 + n] = acc[i][j][r] + bv;
        }
    }
}

// ---------------------------------------------------------------------------
// Merged V-transpose + block stats. grid (NBc, B*H), 256 thr.
// Block nb: transposes V rows [nb*64, nb*64+64) into Vt AND computes the
// nb-th block means (this 64-row span IS stats block nb). Zero-fills the
// nb+32 pad row/col of krep16/vcmpT16.
// ---------------------------------------------------------------------------
__global__ __launch_bounds__(256)
void vtrans_stats_kernel(const unsigned short* __restrict__ Kf,
                         const unsigned short* __restrict__ Vf,
                         unsigned short* __restrict__ Vt,
                         float* __restrict__ krep,
                         unsigned short* __restrict__ krep16,
                         unsigned short* __restrict__ vcmpT16)
{
    __shared__ unsigned short vtile[64][65];
    __shared__ unsigned short ktile[64][65];
    const int nb = blockIdx.x, bh = blockIdx.y;
    const int t0 = nb * BLKc;
    const int tid = threadIdx.x;
    const int c4 = (tid & 15) * 4, r = tid >> 4;   // 16 rows/iter
    const unsigned short* vsrc = Vf + ((size_t)bh * Tc + t0) * HSc;
    const unsigned short* ksrc = Kf + ((size_t)bh * Tc + t0) * HSc;
    #pragma unroll
    for (int it = 0; it < 4; ++it) {
        int tt = r + it * 16;
        *(ushort4*)&vtile[tt][c4] = *(const ushort4*)&vsrc[(size_t)tt * HSc + c4];
        *(ushort4*)&ktile[tt][c4] = *(const ushort4*)&ksrc[(size_t)tt * HSc + c4];
    }
    __syncthreads();
    // transposed V writes
    unsigned short* dst = Vt + (size_t)bh * HSc * Tc + t0;
    #pragma unroll
    for (int it = 0; it < 4; ++it) {
        int d = r + it * 16;
        ushort4 o;
        o.x = vtile[c4 + 0][d]; o.y = vtile[c4 + 1][d];
        o.z = vtile[c4 + 2][d]; o.w = vtile[c4 + 3][d];
        *(ushort4*)&dst[(size_t)d * Tc + c4] = o;
    }
    // block means (wave 0, lane = d)
    if (tid < 64) {
        const int d = tid;
        float sk = 0.f, sv = 0.f;
        #pragma unroll 8
        for (int t = 0; t < BLKc; ++t) {
            sk += h2f(ktile[t][d]);
            sv += h2f(vtile[t][d]);
        }
        float km = sk * (1.0f / BLKc), vm = sv * (1.0f / BLKc);
        krep[((size_t)bh * NBc + nb) * HSc + d] = km;
        krep16[(size_t)bh * 4096 + nb * 64 + d] = f2h(km);
        krep16[(size_t)bh * 4096 + (nb + 32) * 64 + d] = 0;
        vcmpT16[(size_t)bh * 4096 + d * 64 + nb] = f2h(vm);
        vcmpT16[(size_t)bh * 4096 + d * 64 + nb + 32] = 0;
    }
}

// ---------------------------------------------------------------------------
// qbar partials, no cross-lane reduction: phase 1 each lane computes its own
// row's 1/||q|| (independent FMA chain); phase 2 lane=d accumulates
// sum_t q[t][d]*rinv[t] with coalesced loads. Scale x0.125 cancels in qn.
// ---------------------------------------------------------------------------
__global__ __launch_bounds__(64)
void qbar_part_kernel(const unsigned short* __restrict__ Qh, float* __restrict__ qpart)
{
    __shared__ float rinv[64];
    const int ch = blockIdx.x, bh = blockIdx.y, lane = threadIdx.x;
    const int t0 = ch * (Tc / QCH);
    const unsigned short* qbase = Qh + ((size_t)bh * Tc + t0) * HSc;

    // phase 1: own row norm
    {
        const unsigned short* qr = qbase + (size_t)lane * HSc;
        float ss = 0.f;
        #pragma unroll
        for (int d8 = 0; d8 < 8; ++d8) {
            ushort8v v8 = *(const ushort8v*)&qr[d8 * 8];
            #pragma unroll
            for (int j = 0; j < 8; ++j) { float f = h2f(v8[j]); ss += f * f; }
        }
        rinv[lane] = 1.0f / fmaxf(sqrtf(ss), 1e-8f);
    }
    __syncthreads();

    // phase 2: accumulate qn over the 64 rows (lane = d, coalesced)
    float acc = 0.f;
    #pragma unroll 8
    for (int t = 0; t < 64; ++t)
        acc += h2f(qbase[(size_t)t * HSc + lane]) * rinv[t];
    qpart[((size_t)bh * QCH + ch) * HSc + lane] = acc;
}

// ---------------------------------------------------------------------------
// Selection scores + top-8 (descending, ties -> lower index)
// ---------------------------------------------------------------------------
__global__ __launch_bounds__(64)
void topk_kernel(const float* __restrict__ qpart, const float* __restrict__ krep,
                 int* __restrict__ topidx)
{
    int bh = blockIdx.x, lane = threadIdx.x;
    __shared__ float sc[NBc];
    __shared__ float qbs[HSc];
    float qa = 0.0f;
    #pragma unroll
    for (int c = 0; c < QCH; c++)
        qa += qpart[((size_t)bh * QCH + c) * HSc + lane];
    qbs[lane] = qa * (1.0f / Tc);
    __syncthreads();
    if (lane < NBc) {
        float dot = 0, nk = 0;
        for (int d = 0; d < HSc; d++) {
            float kv = krep[((size_t)bh * NBc + lane) * HSc + d];
            nk += kv * kv;
            dot += qbs[d] * kv;
        }
        sc[lane] = dot / fmaxf(sqrtf(nk), 1e-8f);
    }
    __syncthreads();
    if (lane == 0) {
        for (int s = 0; s < NSELc; s++) {
            int best = 0; float bv = sc[0];
            for (int n = 1; n < NBc; n++)
                if (sc[n] > bv) { bv = sc[n]; best = n; }
            topidx[bh * NSELc + s] = best;
            sc[best] = -INFINITY;
        }
    }
}

// ===========================================================================
// MFMA flash attention, constant-shift softmax, ones-MFMA row sums,
// pipelined flat tile loop, dbuf staging, fp16 in/out.
// ===========================================================================
__device__ __forceinline__ void attn_tile3(
    int p0, int wlim, int klim, int qg0,
    const unsigned short* __restrict__ Kh, const unsigned short* __restrict__ Vt,
    unsigned short* __restrict__ Ph,
    half8 aq0, half8 aq1, half8 ones, int wq, int l16, int quad,
    f32x4v o[4], f32x4v& o5)
{
    // ---- QK^T: 8 MFMAs ----
    f32x4v s[4];
    #pragma unroll
    for (int t = 0; t < 4; ++t) {
        f32x4v sa = (f32x4v){0.f, 0.f, 0.f, 0.f};
        half8 b0 = *(const half8*)&Kh[(t * 16 + l16) * LST + quad * 8];
        half8 b1 = *(const half8*)&Kh[(t * 16 + l16) * LST + 32 + quad * 8];
        sa = __builtin_amdgcn_mfma_f32_16x16x32_f16(aq0, b0, sa, 0, 0, 0);
        sa = __builtin_amdgcn_mfma_f32_16x16x32_f16(aq1, b1, sa, 0, 0, 0);
        s[t] = sa;
    }

    // ---- mask + P = exp(s - C) -> Ph (wave-private rows) ----
    #pragma unroll
    for (int t = 0; t < 4; ++t) {
        int kk = t * 16 + l16;
        bool kok = kk < klim;
        int jt = p0 + kk;
        #pragma unroll
        for (int r = 0; r < 4; ++r) {
            int q = qg0 + r;
            bool valid = kok && (jt <= q) && (q - jt <= wlim);
            float p = valid ? __expf(s[t][r] - SOFT_C) : 0.0f;
            Ph[(wq + quad * 4 + r) * LSTP + t * 16 + l16] = f2h(p);
        }
    }

    // NO barrier: Ph write/read is same-wave (lgkmcnt-ordered)

    // ---- PV: 8 MFMAs + 2 ones-MFMAs (row sums into o5) ----
    half8 ap0 = *(const half8*)&Ph[(wq + l16) * LSTP + quad * 8];
    half8 ap1 = *(const half8*)&Ph[(wq + l16) * LSTP + 32 + quad * 8];
    o5 = __builtin_amdgcn_mfma_f32_16x16x32_f16(ap0, ones, o5, 0, 0, 0);
    o5 = __builtin_amdgcn_mfma_f32_16x16x32_f16(ap1, ones, o5, 0, 0, 0);
    #pragma unroll
    for (int dt = 0; dt < 4; ++dt) {
        half8 v0 = *(const half8*)&Vt[(dt * 16 + l16) * LST + quad * 8];
        half8 v1 = *(const half8*)&Vt[(dt * 16 + l16) * LST + 32 + quad * 8];
        o[dt] = __builtin_amdgcn_mfma_f32_16x16x32_f16(ap0, v0, o[dt], 0, 0, 0);
        o[dt] = __builtin_amdgcn_mfma_f32_16x16x32_f16(ap1, v1, o[dt], 0, 0, 0);
    }
}

__global__ __launch_bounds__(256)
void fattn_kernel(const unsigned short* __restrict__ Qh16,
                  const unsigned short* __restrict__ Kf,
                  const unsigned short* __restrict__ Vtg,
                  const unsigned short* __restrict__ krep16,
                  const unsigned short* __restrict__ vcmpT16,
                  const int* __restrict__ topidx,
                  const float* __restrict__ gates, unsigned short* __restrict__ merged)
{
    __shared__ unsigned short KH[2][64 * LST];
    __shared__ unsigned short VT[2][64 * LST];
    __shared__ unsigned short Ph[64 * LSTP];
    __shared__ float gsl[3 * 64];
    __shared__ int tKb[MAXT], tP0[MAXT], tWl[MAXT], tKl[MAXT], tBid[MAXT];

    const int qt = blockIdx.x;      // 0..31
    const int bh = blockIdx.y;      // 0..31
    const int b  = bh >> 4, h = bh & 15;
    const int tid  = threadIdx.x;
    const int wid  = tid >> 6, lane = tid & 63;
    const int l16  = lane & 15, quad = lane >> 4;
    const int q0 = qt * 64;
    const int wq = wid * 16;
    const int qg0 = q0 + wq + quad * 4;   // global q row of reg 0

    const int nslide = (qt < 2 ? qt : 2) + 1;
    const int nsel   = (qt + 1 < NSELc) ? (qt + 1) : NSELc;
    const int nt     = nslide + nsel + 1;

    // ---- Q fragments directly from global fp16 (pre-scaled), ones frag ----
    half8 aq0, aq1, ones;
    {
        const unsigned short* qrow = Qh16 + ((size_t)bh * Tc + q0 + wq + l16) * HSc;
        aq0 = *(const half8*)(qrow + quad * 8);
        aq1 = *(const half8*)(qrow + 32 + quad * 8);
        #pragma unroll
        for (int j = 0; j < 8; ++j) ones[j] = (_Float16)1.0f;
    }

    if (tid < 64) {
        size_t gb = ((size_t)b * Tc + q0 + tid) * 3;
        gsl[0 * 64 + tid] = gates[gb + 0];
        gsl[1 * 64 + tid] = gates[gb + 1];
        gsl[2 * 64 + tid] = gates[gb + 2];
    }
    // ---- build tile descriptor list ----
    if (tid < nt) {
        int i = tid, kb, p0, wl, kl, bid;
        if (i < nslide)            { int tb = q0 - (nslide - 1 - i) * 64;
                                     kb = tb; p0 = tb; wl = WSZ; kl = 64; bid = 0; }
        else if (i < nslide + nsel){ int s = i - nslide;
                                     kb = topidx[bh * NSELc + s] * BLKc;
                                     p0 = s * BLKc; wl = 1 << 30; kl = 64; bid = 1; }
        else                       { kb = 0; p0 = 0; wl = 1 << 30; kl = NBc; bid = 2; }
        tKb[i] = kb; tP0[i] = p0; tWl[i] = wl; tKl[i] = kl; tBid[i] = bid;
    }

    f32x4v o[4], macc[4];
    f32x4v o5 = (f32x4v){0.f, 0.f, 0.f, 0.f};
    #pragma unroll
    for (int dt = 0; dt < 4; ++dt) {
        o[dt]    = (f32x4v){0.f, 0.f, 0.f, 0.f};
        macc[dt] = (f32x4v){0.f, 0.f, 0.f, 0.f};
    }

    const int seg = tid & 7, r0 = tid >> 3;   // 8 segs x 32 rows
    const unsigned short* kbh = Kf  + (size_t)bh * Tc * HSc;
    const unsigned short* vbh = Vtg + (size_t)bh * HSc * Tc;

    // ---- stage tile 0 (always sliding) into buffer 0 ----
    {
        int tb0 = q0 - (nslide - 1) * 64;
        const unsigned short* kp = kbh + (size_t)tb0 * HSc;
        const unsigned short* vp = vbh + tb0;
        ushort8v k0 = *(const ushort8v*)(kp + (size_t)r0 * HSc + seg * 8);
        ushort8v k1 = *(const ushort8v*)(kp + (size_t)(r0 + 32) * HSc + seg * 8);
        ushort8v v0 = *(const ushort8v*)(vp + (size_t)r0 * Tc + seg * 8);
        ushort8v v1 = *(const ushort8v*)(vp + (size_t)(r0 + 32) * Tc + seg * 8);
        *(ushort8v*)&KH[0][r0 * LST + seg * 8] = k0;
        *(ushort8v*)&KH[0][(r0 + 32) * LST + seg * 8] = k1;
        *(ushort8v*)&VT[0][r0 * LST + seg * 8] = v0;
        *(ushort8v*)&VT[0][(r0 + 32) * LST + seg * 8] = v1;
    }
    __syncthreads();   // covers staging, gsl, tile list

    int pb = 0;
    for (int i = 0; i < nt; ++i) {
        const int cb = i & 1;
        const bool pf = (i + 1 < nt);
        ushort8v k0, k1, v0, v1;
        if (pf) {   // issue next tile's global loads (land in regs; used after compute)
            int bid2 = tBid[i + 1], kb2 = tKb[i + 1];
            const unsigned short *kp, *vp;
            int vs;
            if (bid2 < 2) { kp = kbh + (size_t)kb2 * HSc; vp = vbh + kb2; vs = Tc; }
            else          { kp = krep16 + (size_t)bh * 4096;
                            vp = vcmpT16 + (size_t)bh * 4096; vs = 64; }
            k0 = *(const ushort8v*)(kp + (size_t)r0 * HSc + seg * 8);
            k1 = *(const ushort8v*)(kp + (size_t)(r0 + 32) * HSc + seg * 8);
            v0 = *(const ushort8v*)(vp + (size_t)r0 * vs + seg * 8);
            v1 = *(const ushort8v*)(vp + (size_t)(r0 + 32) * vs + seg * 8);
        }
        int bid = tBid[i];
        if (bid != pb) {   // block-uniform branch transition: merge + reset
            #pragma unroll
            for (int r = 0; r < 4; ++r) {
                float inv = gsl[pb * 64 + wq + quad * 4 + r] / o5[r];
                #pragma unroll
                for (int dt = 0; dt < 4; ++dt) { macc[dt][r] += inv * o[dt][r]; o[dt][r] = 0.f; }
                o5[r] = 0.f;
            }
            pb = bid;
        }
        attn_tile3(tP0[i], tWl[i], tKl[i], qg0, KH[cb], VT[cb], Ph,
                   aq0, aq1, ones, wq, l16, quad, o, o5);
        if (pf) {   // write prefetched tile into the other buffer
            *(ushort8v*)&KH[cb ^ 1][r0 * LST + seg * 8] = k0;
            *(ushort8v*)&KH[cb ^ 1][(r0 + 32) * LST + seg * 8] = k1;
            *(ushort8v*)&VT[cb ^ 1][r0 * LST + seg * 8] = v0;
            *(ushort8v*)&VT[cb ^ 1][(r0 + 32) * LST + seg * 8] = v1;
        }
        __syncthreads();
    }
    // final merge (pb == 2)
    #pragma unroll
    for (int r = 0; r < 4; ++r) {
        float inv = gsl[pb * 64 + wq + quad * 4 + r] / o5[r];
        #pragma unroll
        for (int dt = 0; dt < 4; ++dt) macc[dt][r] += inv * o[dt][r];
    }

    // ---- store merged fp16: row q, col h*64 + dt*16 + l16 ----
    #pragma unroll
    for (int r = 0; r < 4; ++r) {
        size_t mrow = (size_t)b * Tc + qg0 + r;
        #pragma unroll
        for (int dt = 0; dt < 4; ++dt)
            merged[mrow * Cc + h * HSc + dt * 16 + l16] = f2h(macc[dt][r]);
    }
}

// ---------------------------------------------------------------------------
extern "C" void kernel_launch(void* const* d_in, const int* in_sizes, int n_in,
                              void* d_out, int out_size, void* d_ws, size_t ws_size,
                              hipStream_t stream)
{
    const float* x  = (const float*)d_in[0];
    const float* Wq = (const float*)d_in[1];
    const float* bq = (const float*)d_in[2];
    const float* Wk = (const float*)d_in[3];
    const float* bk = (const float*)d_in[4];
    const float* Wv = (const float*)d_in[5];
    const float* bv = (const float*)d_in[6];
    const float* Wo = (const float*)d_in[7];
    const float* bo = (const float*)d_in[8];
    const float* Wg = (const float*)d_in[9];
    const float* bg = (const float*)d_in[10];
    float* out = (float*)d_out;
    float* ws  = (float*)d_ws;

    // workspace layout (float offsets)
    unsigned short* Qh16 = (unsigned short*)(ws + 0);        // 4 Mi ushort
    unsigned short* Kf16 = (unsigned short*)(ws + 2097152);  // 4 Mi ushort
    unsigned short* Vf16 = (unsigned short*)(ws + 4194304);  // 4 Mi ushort
    unsigned short* Vt16 = (unsigned short*)(ws + 6291456);  // 4 Mi ushort
    unsigned short* Mgb  = (unsigned short*)(ws + 8388608);  // 4 Mi ushort
    unsigned short* xb   = (unsigned short*)(ws + 10485760); // 4 Mi ushort
    unsigned short* WqkvT = (unsigned short*)(ws + 12582912);// 3 Mi ushort
    unsigned short* WoT   = (unsigned short*)(ws + 14155776);// 1 Mi ushort
    float* gates = ws + 14680064;   // 12288
    float* krep  = ws + 14692352;   // 65536
    unsigned short* krep16  = (unsigned short*)(ws + 14757888); // 131072 ushort
    unsigned short* vcmpT16 = (unsigned short*)(ws + 14823424); // 131072 ushort
    float* qpart = ws + 14888960;   // 65536
    int*   topidx = (int*)(ws + 14954496); // 256 ints

    cvt_gates_kernel<<<4096 + Mrows / 4, 256, 0, stream>>>(x, xb, Wg, bg, gates);
    cvt_wT4_kernel<<<dim3(16, 16, 4), 256, 0, stream>>>(Wq, Wk, Wv, Wo, WqkvT, WoT);

    mfma_gemm_qkv<<<dim3(24, 32), 256, 0, stream>>>(xb, WqkvT, bq, bk, bv,
                                                    Qh16, Kf16, Vf16);
    vtrans_stats_kernel<<<dim3(NBc, Bc * Hc), 256, 0, stream>>>(Kf16, Vf16, Vt16,
                                                                krep, krep16, vcmpT16);
    qbar_part_kernel<<<dim3(QCH, Bc * Hc), 64, 0, stream>>>(Qh16, qpart);
    topk_kernel<<<Bc * Hc, 64, 0, stream>>>(qpart, krep, topidx);
    fattn_kernel<<<dim3(Tc / 64, Bc * Hc), 256, 0, stream>>>(Qh16, Kf16, Vt16,
                                                             krep16, vcmpT16,
                                                             topidx, gates, Mgb);
    mfma_gemm_kernel<<<dim3(8, 64), 256, 0, stream>>>(Mgb, WoT, bo, out);
}